// Round 1
// baseline (56125.342 us; speedup 1.0000x reference)
//
#include <hip/hip_runtime.h>
#include <math.h>

// Problem dims
#define TSTEPS 512
#define BSZ    64
#define INDIM  256
#define HDIM   1024
#define G4     4096   // 4*H

__device__ __forceinline__ float sigm(float x) { return 1.f / (1.f + expf(-x)); }

// =====================================================================
// GEMM partial: C_part[slice][64][N] = Avirt[64, kslice] @ Wvirt[kslice, N]
// Avirt = concat(A0[64,K0] (row stride lda0), A1[64,K1] (row stride lda1))
// Wvirt = concat rows (W0[K0,N], W1[K1,N])
// grid.x = N/64 tiles, grid.y = K slices (each KS long, KS % 32 == 0,
// K0 % 32 == 0 so 32-chunks never straddle the segment boundary).
// block = 256 threads; each thread computes a 4x4 sub-tile.
// =====================================================================
__global__ __launch_bounds__(256) void gemm_part(
    const float* __restrict__ A0, int lda0, int K0, const float* __restrict__ W0,
    const float* __restrict__ A1, int lda1, const float* __restrict__ W1,
    float* __restrict__ Cpart, int N, int KS)
{
    __shared__ float At[32][68];   // A transposed chunk: At[kk][m]
    __shared__ float Ws[32][68];   // W chunk: Ws[kk][nn]

    const int tid = threadIdx.x;
    const int mg  = tid & 15;      // row group: rows mg*4 .. mg*4+3
    const int ng  = tid >> 4;      // col group: cols ng*4 .. ng*4+3
    const int n0  = blockIdx.x * 64;
    const int kbeg = blockIdx.y * KS;
    const int kend = kbeg + KS;

    float acc[4][4] = {};

    for (int kc = kbeg; kc < kend; kc += 32) {
        // ---- stage A chunk (transposed). 32x64 elements, 8 elems/thread.
        // lanes walk kk fastest -> coalesced global reads along k.
#pragma unroll
        for (int r = 0; r < 8; ++r) {
            int lin = r * 256 + tid;
            int kk = lin & 31;
            int m  = lin >> 5;
            int k  = kc + kk;
            float v;
            if (k < K0) v = A0[m * lda0 + k];
            else        v = A1[m * lda1 + (k - K0)];
            At[kk][m] = v;
        }
        // ---- stage W chunk. lanes walk nn fastest -> coalesced along n.
#pragma unroll
        for (int r = 0; r < 8; ++r) {
            int lin = r * 256 + tid;
            int nn = lin & 63;
            int kk = lin >> 6;
            int k  = kc + kk;
            const float* Wrow = (k < K0) ? (W0 + (size_t)k * N)
                                         : (W1 + (size_t)(k - K0) * N);
            Ws[kk][nn] = Wrow[n0 + nn];
        }
        __syncthreads();

#pragma unroll 8
        for (int kk = 0; kk < 32; ++kk) {
            float4 a = *(const float4*)&At[kk][mg * 4];
            float4 w = *(const float4*)&Ws[kk][ng * 4];
            acc[0][0] += a.x * w.x; acc[0][1] += a.x * w.y; acc[0][2] += a.x * w.z; acc[0][3] += a.x * w.w;
            acc[1][0] += a.y * w.x; acc[1][1] += a.y * w.y; acc[1][2] += a.y * w.z; acc[1][3] += a.y * w.w;
            acc[2][0] += a.z * w.x; acc[2][1] += a.z * w.y; acc[2][2] += a.z * w.z; acc[2][3] += a.z * w.w;
            acc[3][0] += a.w * w.x; acc[3][1] += a.w * w.y; acc[3][2] += a.w * w.z; acc[3][3] += a.w * w.w;
        }
        __syncthreads();
    }

    float* Cp = Cpart + (size_t)blockIdx.y * 64 * N;
#pragma unroll
    for (int i = 0; i < 4; ++i) {
        int m = mg * 4 + i;
        float4 v = make_float4(acc[i][0], acc[i][1], acc[i][2], acc[i][3]);
        *(float4*)&Cp[(size_t)m * N + n0 + ng * 4] = v;
    }
}

// =====================================================================
// Cell kernel: one workgroup per batch row (grid = 64, block = 256).
// Reduces K-split partials, adds bias, runs the sLSTM cell + 3 LayerNorms.
// =====================================================================
__device__ __forceinline__ float2 block_sum2(float s, float q, float* red)
{
#pragma unroll
    for (int off = 32; off; off >>= 1) {
        s += __shfl_down(s, off);
        q += __shfl_down(q, off);
    }
    int w = threadIdx.x >> 6;
    if ((threadIdx.x & 63) == 0) { red[w * 2] = s; red[w * 2 + 1] = q; }
    __syncthreads();
    float2 r = make_float2(red[0] + red[2] + red[4] + red[6],
                           red[1] + red[3] + red[5] + red[7]);
    __syncthreads();
    return r;
}

#define LN_EPS 1e-5f

__global__ __launch_bounds__(256) void cell_kernel(
    const float* __restrict__ parts, int nsl,        // [nsl][64][4096]
    const float* __restrict__ bias,                  // [4096]
    const float* __restrict__ resid, int nres,       // [nres][64][1024]
    float* __restrict__ cstate,                      // [64][1024] in/out
    float* __restrict__ hstate,                      // [64][1024] out
    const float* __restrict__ lncg, const float* __restrict__ lncb,
    const float* __restrict__ lnhg, const float* __restrict__ lnhb,
    const float* __restrict__ lnog, const float* __restrict__ lnob,
    float* __restrict__ out_t)                       // optional [64][1024]
{
    __shared__ float red[16];
    const int b = blockIdx.x;
    const int tid = threadIdx.x;

    float cn[4], ov[4], tmp[4];

    // gates + cell state update
#pragma unroll
    for (int j = 0; j < 4; ++j) {
        int n = j * 256 + tid;
        float gi = 0.f, gf = 0.f, gg = 0.f, go = 0.f;
        for (int s = 0; s < nsl; ++s) {
            const float* P = parts + ((size_t)s * 64 + b) * 4096;
            gi += P[n]; gf += P[1024 + n]; gg += P[2048 + n]; go += P[3072 + n];
        }
        gi += bias[n]; gf += bias[1024 + n]; gg += bias[2048 + n]; go += bias[3072 + n];
        float c_old = cstate[b * 1024 + n];
        cn[j] = sigm(gf) * c_old + expf(gi) * tanhf(gg);
        ov[j] = go;
    }

    // LN(c)
    {
        float s = 0.f, q = 0.f;
#pragma unroll
        for (int j = 0; j < 4; ++j) { s += cn[j]; q += cn[j] * cn[j]; }
        float2 r = block_sum2(s, q, red);
        float mean = r.x * (1.f / 1024.f);
        float var  = r.y * (1.f / 1024.f) - mean * mean;
        float rstd = rsqrtf(var + LN_EPS);
#pragma unroll
        for (int j = 0; j < 4; ++j) {
            int n = j * 256 + tid;
            float cl = (cn[j] - mean) * rstd * lncg[n] + lncb[n];
            cstate[b * 1024 + n] = cl;
            tmp[j] = sigm(ov[j]) * tanhf(cl);   // h before LN
        }
    }

    // LN(h)
    {
        float s = 0.f, q = 0.f;
#pragma unroll
        for (int j = 0; j < 4; ++j) { s += tmp[j]; q += tmp[j] * tmp[j]; }
        float2 r = block_sum2(s, q, red);
        float mean = r.x * (1.f / 1024.f);
        float var  = r.y * (1.f / 1024.f) - mean * mean;
        float rstd = rsqrtf(var + LN_EPS);
#pragma unroll
        for (int j = 0; j < 4; ++j) {
            int n = j * 256 + tid;
            float hl = (tmp[j] - mean) * rstd * lnhg[n] + lnhb[n];
            float rs = 0.f;
            for (int s2 = 0; s2 < nres; ++s2)
                rs += resid[((size_t)s2 * 64 + b) * 1024 + n];
            tmp[j] = hl + rs;                    // h + residual, before outer LN
        }
    }

    // LN(h + resid)
    {
        float s = 0.f, q = 0.f;
#pragma unroll
        for (int j = 0; j < 4; ++j) { s += tmp[j]; q += tmp[j] * tmp[j]; }
        float2 r = block_sum2(s, q, red);
        float mean = r.x * (1.f / 1024.f);
        float var  = r.y * (1.f / 1024.f) - mean * mean;
        float rstd = rsqrtf(var + LN_EPS);
#pragma unroll
        for (int j = 0; j < 4; ++j) {
            int n = j * 256 + tid;
            float hn = (tmp[j] - mean) * rstd * lnog[n] + lnob[n];
            hstate[b * 1024 + n] = hn;
            if (out_t) out_t[b * 1024 + n] = hn;
        }
    }
}

__global__ void zero_states(float* p)
{
    int i = blockIdx.x * 256 + threadIdx.x;   // grid 1024 x 256 = 262144
    p[i] = 0.f;
}

__global__ void final_copy(const float* __restrict__ h0, const float* __restrict__ h1,
                           const float* __restrict__ c0, const float* __restrict__ c1,
                           float* __restrict__ out)
{
    int i = blockIdx.x * 256 + threadIdx.x;   // grid 256 x 256 = 65536
    out[i]          = h0[i];
    out[65536 + i]  = h1[i];
    out[131072 + i] = c0[i];
    out[196608 + i] = c1[i];
}

// =====================================================================
extern "C" void kernel_launch(void* const* d_in, const int* in_sizes, int n_in,
                              void* d_out, int out_size, void* d_ws, size_t ws_size,
                              hipStream_t stream)
{
    const float* x     = (const float*)d_in[0];
    const float* Wproj = (const float*)d_in[1];
    const float* Wx0   = (const float*)d_in[2];
    const float* Wh0   = (const float*)d_in[3];
    const float* b0    = (const float*)d_in[4];
    const float* Wx1   = (const float*)d_in[5];
    const float* Wh1   = (const float*)d_in[6];
    const float* b1    = (const float*)d_in[7];
    const float* lnc_g = (const float*)d_in[8];
    const float* lnc_b = (const float*)d_in[9];
    const float* lnh_g = (const float*)d_in[10];
    const float* lnh_b = (const float*)d_in[11];
    const float* lno_g = (const float*)d_in[12];
    const float* lno_b = (const float*)d_in[13];
    float* out = (float*)d_out;

    float* ws     = (float*)d_ws;
    float* parts0 = ws;                         // 4*64*4096
    float* parts1 = parts0 + 4 * 64 * 4096;     // 4*64*4096
    float* partsr = parts1 + 4 * 64 * 4096;     // 2*64*1024
    float* h0     = partsr + 2 * 64 * 1024;     // 64*1024
    float* c0     = h0 + 65536;
    float* h1     = c0 + 65536;
    float* c1     = h1 + 65536;

    zero_states<<<dim3(1024), 256, 0, stream>>>(h0);   // h0,c0,h1,c1 contiguous

    for (int t = 0; t < TSTEPS; ++t) {
        const float* xt = x + (size_t)t * BSZ * INDIM;

        // gates0 partials: [x_t | h0] @ [Wx0; Wh0], K = 256+1024 = 1280, 4 slices of 320
        gemm_part<<<dim3(64, 4), 256, 0, stream>>>(
            xt, INDIM, INDIM, Wx0, h0, HDIM, Wh0, parts0, G4, 320);
        // r0 partials: x_t @ Wproj, K = 256, 2 slices of 128
        gemm_part<<<dim3(16, 2), 256, 0, stream>>>(
            xt, INDIM, INDIM, Wproj, nullptr, 0, nullptr, partsr, HDIM, 128);
        // layer-0 cell (reduces partials, bias, cell math, 3 LNs)
        cell_kernel<<<64, 256, 0, stream>>>(
            parts0, 4, b0, partsr, 2, c0, h0,
            lnc_g, lnc_b, lnh_g, lnh_b, lno_g, lno_b, nullptr);
        // gates1 partials: [h0_new | h1] @ [Wx1; Wh1], K = 2048, 4 slices of 512
        gemm_part<<<dim3(64, 4), 256, 0, stream>>>(
            h0, HDIM, HDIM, Wx1, h1, HDIM, Wh1, parts1, G4, 512);
        // layer-1 cell, residual = new h0, writes output row
        cell_kernel<<<64, 256, 0, stream>>>(
            parts1, 4, b1, h0, 1, c1, h1,
            lnc_g + HDIM, lnc_b + HDIM, lnh_g + HDIM, lnh_b + HDIM,
            lno_g + HDIM, lno_b + HDIM, out + (size_t)t * BSZ * HDIM);
    }

    final_copy<<<dim3(256), 256, 0, stream>>>(
        h0, h1, c0, c1, out + (size_t)TSTEPS * BSZ * HDIM);
}

// Round 3
// 43183.682 us; speedup vs baseline: 1.2997x; 1.2997x over previous
//
#include <hip/hip_runtime.h>
#include <math.h>

// Problem dims
#define TSTEPS 512
#define BSZ    64
#define INDIM  256
#define HDIM   1024
#define G4     4096
#define N0TOT  5120   // 4096 gate cols + 1024 proj cols
#define K0TOT  1280   // 256 (x) + 1024 (h0)
#define K1TOT  2048   // 1024 (h0') + 1024 (h1)
#define LN_EPS 1e-5f

typedef short  s8v  __attribute__((ext_vector_type(8)));
typedef float  f4v  __attribute__((ext_vector_type(4)));

__device__ __forceinline__ unsigned short f2bf(float f) {
    unsigned u = __float_as_uint(f);
    u += 0x7FFFu + ((u >> 16) & 1u);        // round-to-nearest-even
    return (unsigned short)(u >> 16);
}
__device__ __forceinline__ float bf2f(unsigned short h) {
    return __uint_as_float(((unsigned)h) << 16);
}
__device__ __forceinline__ float sigm(float x) { return 1.f / (1.f + expf(-x)); }

// =====================================================================
// Split-precision bf16 MFMA GEMM partial:
//   Cpart[slice][64][N] = Avirt[64, kslice] @ W[kslice, N]
// A and W are stored as hi+lo bf16 pairs (value = hi + lo, ~fp32 accuracy).
// Product = a_hi*b_hi + a_hi*b_lo + a_lo*b_hi  (a_lo*b_lo dropped, ~2^-18).
// Avirt = concat(A0[64,K0] (stride lda0), A1 (stride lda1)); A0lo may be
// nullptr (x input kept single-bf16 -> skip the a_lo term in that segment).
// W given TRANSPOSED: Wt[N][Ktot] so B-fragments are contiguous 16B loads.
// Each block: 4 waves; wave w computes rows 16w..16w+15 x 32 cols.
// grid.x = N/32, grid.y = K slices of KS. Tiles with n0 >= nKlimStart only
// accumulate k < klimSmall (proj columns); slices fully above write zeros.
// MFMA 16x16x32 bf16 mapping (verified round 2: quantization-scale error):
//   A: lane l holds A[l&15][8*(l>>4)+i]  B: Wt[n0+sub*16+(l&15)][k..k+7]
//   D: lane l, reg r -> row 4*(l>>4)+r, col l&15
// =====================================================================
__global__ __launch_bounds__(256) void mfma_gemm(
    const unsigned short* __restrict__ A0hi, const unsigned short* __restrict__ A0lo,
    int lda0, int K0,
    const unsigned short* __restrict__ A1hi, const unsigned short* __restrict__ A1lo,
    int lda1,
    const unsigned short* __restrict__ Wthi, const unsigned short* __restrict__ Wtlo,
    int ldw, int Ktot,
    float* __restrict__ Cpart, int N, int KS,
    int nKlimStart, int klimSmall)
{
    const int lane = threadIdx.x & 63;
    const int wv   = threadIdx.x >> 6;
    const int row  = lane & 15;
    const int kg   = lane >> 4;
    const int n0   = blockIdx.x * 32;

    int kbeg = blockIdx.y * KS;
    int kend = kbeg + KS;
    int klim = (n0 >= nKlimStart) ? klimSmall : Ktot;
    if (kend > klim) kend = klim;

    f4v acc0 = {0.f, 0.f, 0.f, 0.f};
    f4v acc1 = {0.f, 0.f, 0.f, 0.f};

    const int arow = wv * 16 + row;
    const unsigned short* wrh0 = Wthi + (size_t)(n0 + row) * ldw;
    const unsigned short* wrl0 = Wtlo + (size_t)(n0 + row) * ldw;
    const unsigned short* wrh1 = Wthi + (size_t)(n0 + 16 + row) * ldw;
    const unsigned short* wrl1 = Wtlo + (size_t)(n0 + 16 + row) * ldw;

    for (int kc = kbeg; kc < kend; kc += 32) {
        int kk = kc + kg * 8;
        const unsigned short* ahp;
        const unsigned short* alp;
        if (kc < K0) {
            size_t off = (size_t)arow * lda0 + kk;
            ahp = A0hi + off;
            alp = A0lo ? (A0lo + off) : nullptr;
        } else {
            size_t off = (size_t)arow * lda1 + (kk - K0);
            ahp = A1hi + off;
            alp = A1lo + off;
        }
        s8v ah  = *(const s8v*)ahp;
        s8v bh0 = *(const s8v*)(wrh0 + kc);
        s8v bl0 = *(const s8v*)(wrl0 + kc);
        s8v bh1 = *(const s8v*)(wrh1 + kc);
        s8v bl1 = *(const s8v*)(wrl1 + kc);
        // NOTE: b fragment k-offset within chunk is kg*8 too:
        // (wrh0 + kc) is wrong unless we add kg*8 -- use kk-based address.
        bh0 = *(const s8v*)(wrh0 + kk - ((kc < K0) ? 0 : 0));
        (void)bh0;
        // recompute properly below
        s8v Bh0 = *(const s8v*)(wrh0 + kk);
        s8v Bl0 = *(const s8v*)(wrl0 + kk);
        s8v Bh1 = *(const s8v*)(wrh1 + kk);
        s8v Bl1 = *(const s8v*)(wrl1 + kk);
        acc0 = __builtin_amdgcn_mfma_f32_16x16x32_bf16(ah, Bh0, acc0, 0, 0, 0);
        acc1 = __builtin_amdgcn_mfma_f32_16x16x32_bf16(ah, Bh1, acc1, 0, 0, 0);
        acc0 = __builtin_amdgcn_mfma_f32_16x16x32_bf16(ah, Bl0, acc0, 0, 0, 0);
        acc1 = __builtin_amdgcn_mfma_f32_16x16x32_bf16(ah, Bl1, acc1, 0, 0, 0);
        if (alp) {
            s8v al = *(const s8v*)alp;
            acc0 = __builtin_amdgcn_mfma_f32_16x16x32_bf16(al, Bh0, acc0, 0, 0, 0);
            acc1 = __builtin_amdgcn_mfma_f32_16x16x32_bf16(al, Bh1, acc1, 0, 0, 0);
        }
    }

    float* Cp = Cpart + (size_t)blockIdx.y * 64 * N;
#pragma unroll
    for (int r = 0; r < 4; ++r) {
        int brow = wv * 16 + kg * 4 + r;
        Cp[(size_t)brow * N + n0 + row]      = acc0[r];
        Cp[(size_t)brow * N + n0 + 16 + row] = acc1[r];
    }
}

// =====================================================================
// Tiled transpose + fp32 -> split bf16 (hi+lo):
//   dsthi/lo[(n+noff)*ldd + koff + k] = split(src[k][n])
// block 256 = (32 x 8), 32x32 tiles, grid (N/32, K/32)
// =====================================================================
__global__ __launch_bounds__(256) void transpose_split(
    const float* __restrict__ src, int N,
    unsigned short* __restrict__ dsthi, unsigned short* __restrict__ dstlo,
    int ldd, int noff, int koff)
{
    __shared__ float tile[32][33];
    const int n0 = blockIdx.x * 32, k0 = blockIdx.y * 32;
    const int tx = threadIdx.x & 31, ty = threadIdx.x >> 5;
#pragma unroll
    for (int i = 0; i < 4; ++i)
        tile[ty + i * 8][tx] = src[(size_t)(k0 + ty + i * 8) * N + n0 + tx];
    __syncthreads();
#pragma unroll
    for (int i = 0; i < 4; ++i) {
        float v = tile[tx][ty + i * 8];
        unsigned short hi = f2bf(v);
        unsigned short lo = f2bf(v - bf2f(hi));
        size_t idx = (size_t)(n0 + ty + i * 8 + noff) * ldd + k0 + koff + tx;
        dsthi[idx] = hi;
        dstlo[idx] = lo;
    }
}

__global__ void conv_bf16(const float* __restrict__ src,
                          unsigned short* __restrict__ dst, int n4)
{
    int i = blockIdx.x * 256 + threadIdx.x;
    if (i < n4) {
        float4 v = ((const float4*)src)[i];
        ushort4 o;
        o.x = f2bf(v.x); o.y = f2bf(v.y); o.z = f2bf(v.z); o.w = f2bf(v.w);
        ((ushort4*)dst)[i] = o;
    }
}

// =====================================================================
// Cell kernel: one workgroup per batch row (grid 64, block 256).
// Sums 2 K-slice partials + bias, sLSTM cell, LN(c), LN(h), +resid, LN.
// Writes fp32 h state + split bf16 h (next GEMM's A operand), optional out.
// =====================================================================
__device__ __forceinline__ float2 block_sum2(float s, float q, float* red)
{
#pragma unroll
    for (int off = 32; off; off >>= 1) {
        s += __shfl_down(s, off);
        q += __shfl_down(q, off);
    }
    int w = threadIdx.x >> 6;
    if ((threadIdx.x & 63) == 0) { red[w * 2] = s; red[w * 2 + 1] = q; }
    __syncthreads();
    float2 r = make_float2(red[0] + red[2] + red[4] + red[6],
                           red[1] + red[3] + red[5] + red[7]);
    __syncthreads();
    return r;
}

__global__ __launch_bounds__(256) void cell_kernel(
    const float* __restrict__ parts, int pstride,     // [2][64][pstride]
    const float* __restrict__ bias,                   // [4096]
    const float* __restrict__ resid, int rstride, long rslice, int nres,
    float* __restrict__ cstate,                       // [64][1024] in/out
    float* __restrict__ hstate,                       // [64][1024] out (fp32)
    unsigned short* __restrict__ hhi,                 // [64][1024] out bf16 hi
    unsigned short* __restrict__ hlo,                 // [64][1024] out bf16 lo
    const float* __restrict__ lncg, const float* __restrict__ lncb,
    const float* __restrict__ lnhg, const float* __restrict__ lnhb,
    const float* __restrict__ lnog, const float* __restrict__ lnob,
    float* __restrict__ out_t)
{
    __shared__ float red[16];
    const int b = blockIdx.x;
    const int tid = threadIdx.x;

    float cn[4], ov[4], tmp[4];

#pragma unroll
    for (int j = 0; j < 4; ++j) {
        int n = j * 256 + tid;
        const float* P0 = parts + (size_t)b * pstride;
        const float* P1 = parts + ((size_t)64 + b) * pstride;
        float gi = P0[n]        + P1[n]        + bias[n];
        float gf = P0[1024 + n] + P1[1024 + n] + bias[1024 + n];
        float gg = P0[2048 + n] + P1[2048 + n] + bias[2048 + n];
        float go = P0[3072 + n] + P1[3072 + n] + bias[3072 + n];
        float c_old = cstate[b * 1024 + n];
        cn[j] = sigm(gf) * c_old + expf(gi) * tanhf(gg);
        ov[j] = go;
    }

    // LN(c)
    {
        float s = 0.f, q = 0.f;
#pragma unroll
        for (int j = 0; j < 4; ++j) { s += cn[j]; q += cn[j] * cn[j]; }
        float2 r = block_sum2(s, q, red);
        float mean = r.x * (1.f / 1024.f);
        float var  = r.y * (1.f / 1024.f) - mean * mean;
        float rstd = rsqrtf(var + LN_EPS);
#pragma unroll
        for (int j = 0; j < 4; ++j) {
            int n = j * 256 + tid;
            float cl = (cn[j] - mean) * rstd * lncg[n] + lncb[n];
            cstate[b * 1024 + n] = cl;
            tmp[j] = sigm(ov[j]) * tanhf(cl);
        }
    }

    // LN(h)
    {
        float s = 0.f, q = 0.f;
#pragma unroll
        for (int j = 0; j < 4; ++j) { s += tmp[j]; q += tmp[j] * tmp[j]; }
        float2 r = block_sum2(s, q, red);
        float mean = r.x * (1.f / 1024.f);
        float var  = r.y * (1.f / 1024.f) - mean * mean;
        float rstd = rsqrtf(var + LN_EPS);
#pragma unroll
        for (int j = 0; j < 4; ++j) {
            int n = j * 256 + tid;
            float hl = (tmp[j] - mean) * rstd * lnhg[n] + lnhb[n];
            float rs = 0.f;
            for (int s2 = 0; s2 < nres; ++s2)
                rs += resid[s2 * rslice + (size_t)b * rstride + n];
            tmp[j] = hl + rs;
        }
    }

    // LN(h + resid)
    {
        float s = 0.f, q = 0.f;
#pragma unroll
        for (int j = 0; j < 4; ++j) { s += tmp[j]; q += tmp[j] * tmp[j]; }
        float2 r = block_sum2(s, q, red);
        float mean = r.x * (1.f / 1024.f);
        float var  = r.y * (1.f / 1024.f) - mean * mean;
        float rstd = rsqrtf(var + LN_EPS);
#pragma unroll
        for (int j = 0; j < 4; ++j) {
            int n = j * 256 + tid;
            float hn = (tmp[j] - mean) * rstd * lnog[n] + lnob[n];
            hstate[b * 1024 + n] = hn;
            unsigned short hi = f2bf(hn);
            hhi[b * 1024 + n] = hi;
            hlo[b * 1024 + n] = f2bf(hn - bf2f(hi));
            if (out_t) out_t[b * 1024 + n] = hn;
        }
    }
}

__global__ void final_copy(const float* __restrict__ h0, const float* __restrict__ h1,
                           const float* __restrict__ c0, const float* __restrict__ c1,
                           float* __restrict__ out)
{
    int i = blockIdx.x * 256 + threadIdx.x;   // 256 x 256 = 65536
    out[i]          = h0[i];
    out[65536 + i]  = h1[i];
    out[131072 + i] = c0[i];
    out[196608 + i] = c1[i];
}

// =====================================================================
extern "C" void kernel_launch(void* const* d_in, const int* in_sizes, int n_in,
                              void* d_out, int out_size, void* d_ws, size_t ws_size,
                              hipStream_t stream)
{
    const float* x     = (const float*)d_in[0];
    const float* Wproj = (const float*)d_in[1];
    const float* Wx0   = (const float*)d_in[2];
    const float* Wh0   = (const float*)d_in[3];
    const float* b0    = (const float*)d_in[4];
    const float* Wx1   = (const float*)d_in[5];
    const float* Wh1   = (const float*)d_in[6];
    const float* b1    = (const float*)d_in[7];
    const float* lnc_g = (const float*)d_in[8];
    const float* lnc_b = (const float*)d_in[9];
    const float* lnh_g = (const float*)d_in[10];
    const float* lnh_b = (const float*)d_in[11];
    const float* lno_g = (const float*)d_in[12];
    const float* lno_b = (const float*)d_in[13];
    float* out = (float*)d_out;

    // ---- ws layout (bytes, 16B aligned). total ~83 MB ----
    char* base = (char*)d_ws;
    unsigned short* x_bf   = (unsigned short*)(base);                 // 16,777,216
    unsigned short* W0thi  = (unsigned short*)(base + 16777216);      // 13,107,200
    unsigned short* W0tlo  = (unsigned short*)(base + 29884416);      // 13,107,200
    unsigned short* W1thi  = (unsigned short*)(base + 42991616);      // 16,777,216
    unsigned short* W1tlo  = (unsigned short*)(base + 59768832);      // 16,777,216
    float*          parts0 = (float*)(base + 76546048);               //  2,621,440
    float*          parts1 = (float*)(base + 79167488);               //  2,097,152
    float*          h0     = (float*)(base + 81264640);               // 262,144
    float*          c0     = h0 + 65536;
    float*          h1     = c0 + 65536;
    float*          c1     = h1 + 65536;
    unsigned short* h0hi   = (unsigned short*)(c1 + 65536);           // 131,072 each
    unsigned short* h0lo   = h0hi + 65536;
    unsigned short* h1hi   = h0lo + 65536;
    unsigned short* h1lo   = h1hi + 65536;

    // ---- one-time prep (recomputed every call: deterministic) ----
    conv_bf16<<<dim3(8192), 256, 0, stream>>>(x, x_bf, 2097152);
    hipMemsetAsync(W0thi, 0, (size_t)2 * 5120 * 1280 * 2, stream);    // hi+lo pad
    // W0t[n][k]: n<4096: k<256 Wx0[k][n], k>=256 Wh0[k-256][n]
    //            n>=4096: k<256 Wproj[k][n-4096], else 0
    transpose_split<<<dim3(128, 8),  256, 0, stream>>>(Wx0,   G4,   W0thi, W0tlo, K0TOT, 0,    0);
    transpose_split<<<dim3(128, 32), 256, 0, stream>>>(Wh0,   G4,   W0thi, W0tlo, K0TOT, 0,    256);
    transpose_split<<<dim3(32, 8),   256, 0, stream>>>(Wproj, HDIM, W0thi, W0tlo, K0TOT, 4096, 0);
    // W1t[n][k]: k<1024 Wx1[k][n], else Wh1[k-1024][n]
    transpose_split<<<dim3(128, 32), 256, 0, stream>>>(Wx1,   G4,   W1thi, W1tlo, K1TOT, 0,    0);
    transpose_split<<<dim3(128, 32), 256, 0, stream>>>(Wh1,   G4,   W1thi, W1tlo, K1TOT, 0,    1024);
    // zero h0,c0,h1,c1 (fp32) + h0hi/lo,h1hi/lo (bf16) — contiguous
    hipMemsetAsync(h0, 0, (size_t)4 * 65536 * 4 + 4 * 65536 * 2, stream);

    for (int t = 0; t < TSTEPS; ++t) {
        const unsigned short* xt_bf = x_bf + (size_t)t * BSZ * INDIM;

        // GEMM0: [xt | h0] @ W0t -> parts0[2][64][5120]
        // (cols 4096..5119 = xt@Wproj, K-limited to 256)
        mfma_gemm<<<dim3(160, 2), 256, 0, stream>>>(
            xt_bf, nullptr, INDIM, INDIM, h0hi, h0lo, HDIM,
            W0thi, W0tlo, K0TOT, K0TOT, parts0, N0TOT, 640, 4096, 256);

        cell_kernel<<<64, 256, 0, stream>>>(
            parts0, N0TOT, b0,
            parts0 + 4096, N0TOT, (long)64 * N0TOT, 2,
            c0, h0, h0hi, h0lo,
            lnc_g, lnc_b, lnh_g, lnh_b, lno_g, lno_b, nullptr);

        // GEMM1: [h0' | h1] @ W1t -> parts1[2][64][4096]
        mfma_gemm<<<dim3(128, 2), 256, 0, stream>>>(
            h0hi, h0lo, HDIM, HDIM, h1hi, h1lo, HDIM,
            W1thi, W1tlo, K1TOT, K1TOT, parts1, G4, 1024, 1 << 30, 0);

        cell_kernel<<<64, 256, 0, stream>>>(
            parts1, G4, b1,
            h0, HDIM, 0, 1,
            c1, h1, h1hi, h1lo,
            lnc_g + HDIM, lnc_b + HDIM, lnh_g + HDIM, lnh_b + HDIM,
            lno_g + HDIM, lno_b + HDIM,
            out + (size_t)t * BSZ * HDIM);
    }

    final_copy<<<dim3(256), 256, 0, stream>>>(
        h0, h1, c0, c1, out + (size_t)TSTEPS * BSZ * HDIM);
}